// Round 11
// baseline (328.768 us; speedup 1.0000x reference)
//
#include <hip/hip_runtime.h>
#include <stdint.h>

// ---------------- types ----------------
typedef unsigned short ush;
typedef __bf16   bf16x8 __attribute__((ext_vector_type(8)));
typedef float    f32x4  __attribute__((ext_vector_type(4)));
typedef uint32_t u32x4  __attribute__((ext_vector_type(4)));

union U16B { u32x4 u; bf16x8 b; };
union P8   { ush us[8]; u32x4 v; };

__device__ __forceinline__ ush f2bf(float f) {
    union { float f; uint32_t u; } v; v.f = f;
    uint32_t r = v.u + 0x7FFFu + ((v.u >> 16) & 1u);   // RNE
    return (ush)(r >> 16);
}

__device__ __forceinline__ void gl_lds16(const ush* g, ush* l) {
    __builtin_amdgcn_global_load_lds(
        (const __attribute__((address_space(1))) uint32_t*)g,
        (__attribute__((address_space(3))) uint32_t*)l, 16, 0, 0);
}

// problem constants
#define HWPX  3136
// ws layout (bytes)
#define POOL_OFF   58720256UL   // 8192 f32
#define ATT_OFF    58753024UL   // 16384 f32
#define WAGG_OFF   58818560UL   // 32*9*256*256 bf16

// ---------------- kernel 0: zero xT halo cols {0,57} + pooled ----------------
__global__ void k_halo(u32x4* __restrict__ xT16, u32x4* __restrict__ pooled16) {
    int i = blockIdx.x * 256 + threadIdx.x;        // 448 blocks -> 114688
    int rl = i >> 3, s = i & 7;
    u32x4 z = (u32x4)(0u);
    size_t byte = (size_t)rl * 4096 + (s < 4 ? s * 16 : 3648 + (s - 4) * 16);
    xT16[byte >> 4] = z;
    if (blockIdx.x < 8) pooled16[blockIdx.x * 256 + threadIdx.x] = z;  // full 32KB
}

// ---------------- kernel 1: transpose x -> xT bf16 (swizzled) + pooled sums --
// xT layout: [b][icg32 0..7][row 0..55][padcol 0..63][ic 0..31]
//   padcol p: p=0 and p=57 are zero halo; p=1..56 <-> image col p-1; 58..63 dead
//   sub 's' stored at slot s ^ ((p>>1)&3): injective on every 8-col window
__global__ void k_transpose(const float* __restrict__ x, ush* __restrict__ xT,
                            float* __restrict__ pooled) {
    __shared__ float tile[64][65];
    int blk = blockIdx.x;                 // 32 * 4 * 49
    int b   = blk / 196;
    int rem = blk % 196;
    int icg = rem / 49;                   // 64-ic group
    int pxg = rem % 49;                   // 64-px group
    int t = threadIdx.x;

    {
        int icl  = t >> 2, part = t & 3;
        const float* src = x + (size_t)(b * 256 + icg * 64 + icl) * HWPX + pxg * 64 + part * 16;
        #pragma unroll
        for (int k = 0; k < 4; ++k) {
            f32x4 v = *(const f32x4*)(src + k * 4);
            tile[icl][part * 16 + k * 4 + 0] = v[0];
            tile[icl][part * 16 + k * 4 + 1] = v[1];
            tile[icl][part * 16 + k * 4 + 2] = v[2];
            tile[icl][part * 16 + k * 4 + 3] = v[3];
        }
    }
    __syncthreads();

    if (t < 64) {
        float s = 0.f;
        #pragma unroll 8
        for (int p = 0; p < 64; ++p) s += tile[t][p];
        atomicAdd(pooled + b * 256 + icg * 64 + t, s);
    }

    {
        int pxl = t >> 2, icq = t & 3;
        int px  = pxg * 64 + pxl;
        int row = px / 56;
        int col = px - row * 56;
        int p   = col + 1;
        int xorp = (p >> 1) & 3;
        int icg32   = icg * 2 + (icq >> 1);
        int subbase = (icq & 1) * 2;
        P8 lo, hi;
        #pragma unroll
        for (int m = 0; m < 8; ++m) {
            lo.us[m] = f2bf(tile[icq * 16 + m][pxl]);
            hi.us[m] = f2bf(tile[icq * 16 + 8 + m][pxl]);
        }
        size_t base = (((size_t)(b * 8 + icg32) * 56 + row) * 64 + p) * 32;
        *(u32x4*)(xT + base + (size_t)((subbase ^ xorp) * 8))       = lo.v;
        *(u32x4*)(xT + base + (size_t)(((subbase + 1) ^ xorp) * 8)) = hi.v;
    }
}

// ---------------- kernel 2: attention (1 block, 512 threads) ----------------
__global__ void k_attn(const float* __restrict__ pooled,
                       const float* __restrict__ fc1_w, const float* __restrict__ fc1_b,
                       const float* __restrict__ ln_g,  const float* __restrict__ ln_b,
                       const float* __restrict__ sp_w,  const float* __restrict__ sp_b,
                       float* __restrict__ att) {
    __shared__ float hs[32][16];
    int t = threadIdx.x;
    {
        int b = t >> 4, j = t & 15;
        float acc = 0.f;
        for (int c = 0; c < 256; ++c) acc += pooled[b * 256 + c] * fc1_w[j * 256 + c];
        hs[b][j] = fc1_b[j] + acc * (1.0f / 3136.0f);
    }
    __syncthreads();
    if (t < 32) {
        float mu = 0.f;
        #pragma unroll
        for (int j = 0; j < 16; ++j) mu += hs[t][j];
        mu *= (1.0f / 16.0f);
        float var = 0.f;
        #pragma unroll
        for (int j = 0; j < 16; ++j) { float d = hs[t][j] - mu; var += d * d; }
        var *= (1.0f / 16.0f);
        float inv = rsqrtf(var + 1e-5f);
        #pragma unroll
        for (int j = 0; j < 16; ++j) {
            float v = (hs[t][j] - mu) * inv * ln_g[j] + ln_b[j];
            hs[t][j] = fmaxf(v, 0.f);
        }
    }
    __syncthreads();
    {
        int b = t >> 4, m = t & 15;
        float a[33];
        #pragma unroll 1
        for (int i = 0; i < 33; ++i) {
            int p = m * 33 + i;
            float acc = sp_b[p];
            #pragma unroll
            for (int j = 0; j < 16; ++j) acc += hs[b][j] * sp_w[p * 16 + j];
            a[i] = acc;
        }
        float s = 0.f;
        #pragma unroll
        for (int i = 0; i < 33; ++i) s += fabsf(a[i]);
        float inv = 1.0f / (s + 0.001f);
        #pragma unroll
        for (int c = 0; c < 32; ++c) att[(b * 16 + m) * 32 + c] = a[c] * inv;
    }
}

// ---------------- kernel 3: aggregate weights -> Wagg bf16 [b][tap][oc][ic] --
__global__ void k_agg(const float* __restrict__ cells, const float* __restrict__ att,
                      ush* __restrict__ wagg) {
    __shared__ float at[512];
    int blk = blockIdx.x;                 // 32*64
    int b = blk >> 6, co = blk & 63;
    int t = threadIdx.x;
    for (int i = t; i < 512; i += 256) at[i] = att[b * 512 + i];
    __syncthreads();
    int ci = t & 63, gi = t >> 6;
    float acc[4][9];
    #pragma unroll
    for (int g = 0; g < 4; ++g)
        #pragma unroll
        for (int k = 0; k < 9; ++k) acc[g][k] = 0.f;
    for (int c = 0; c < 32; ++c) {
        float a0 = at[(0 + gi) * 32 + c];
        float a1 = at[(4 + gi) * 32 + c];
        float a2 = at[(8 + gi) * 32 + c];
        float a3 = at[(12 + gi) * 32 + c];
        const float* cp = cells + (size_t)c * 36864 + co * 576 + ci * 9;
        #pragma unroll
        for (int k = 0; k < 9; ++k) {
            float cv = cp[k];
            acc[0][k] += a0 * cv; acc[1][k] += a1 * cv;
            acc[2][k] += a2 * cv; acc[3][k] += a3 * cv;
        }
    }
    #pragma unroll
    for (int g = 0; g < 4; ++g)
        #pragma unroll
        for (int k = 0; k < 9; ++k)
            wagg[((size_t)(b * 9 + k) * 256 + g * 64 + co) * 256 + gi * 64 + ci] = f2bf(acc[g][k]);
}

// ---------------- kernel 4: conv, T3/T4 overlapped pipeline ----------------
// block = 448 px (8 rows) x 128 oc; 512 threads, 8 waves = 4 px-quarters x 2
// oc-halves; 1 block/CU (2 waves/SIMD).
// LDS: x DOUBLE-buffer [2][10 rows][64 cols][32 ic]   = 81,920 B
//      w single        [9 taps][4 slots][128 oc^swz]  = 73,728 B  (155,648 tot)
// Per chunk: {issue w->reg + x->DMA(buf^1)} BEFORE compute; 9-tap compute on
// buf; lgkmcnt(0); s_barrier; ds_write w (vmcnt waits only the w loads, DMAs
// stay in flight); vmcnt(0) (covered by full compute phase); s_barrier.
// w LDS swizzle: item(tap,s,oc) at tap*8192 + s*2048 + (oc^(s<<2))*16 B ->
// write side (lane=(oc,s)) and read side (lane=(l15,s4)) both 2/bank = free.
__global__ __launch_bounds__(512, 1) void k_conv(const ush* __restrict__ xT,
                                                 const ush* __restrict__ wagg,
                                                 float* __restrict__ out) {
    __shared__ __align__(16) ush xs[2][20480];   // 81,920 B
    __shared__ __align__(16) ush wsh[36864];     // 73,728 B

    int tid = threadIdx.x;
    int wg  = blockIdx.x;                // 448
    int xcd = wg & 7;
    int kk  = wg >> 3;                   // 0..55
    int gq  = kk / 7;                    // 0..7
    int sp  = kk - gq * 7;               // spatial tile 0..6 (8 rows)
    int g   = gq * 8 + xcd;              // 0..63
    int b   = g >> 1, octile = g & 1;
    int row0 = sp * 8, oc0 = octile * 128;

    int lane = tid & 63, w = tid >> 6;   // 8 waves
    int ocH = w & 1, pxq = w >> 1;       // oc half (64), px quarter (112)
    int l15 = lane & 15, s4 = lane >> 4;

    {   // zero both x buffers once (invalid halo rows stay zero forever)
        u32x4 z = (u32x4)(0u);
        #pragma unroll
        for (int i = 0; i < 10; ++i) ((u32x4*)xs)[tid + i * 512] = z;
    }

    int prow[7], pq[7];
    #pragma unroll
    for (int j = 0; j < 7; ++j) {
        int px = pxq * 112 + j * 16 + l15;           // 0..447
        prow[j] = px / 56;                           // 0..7
        pq[j]   = px - prow[j] * 56;
    }

    unsigned vmask = 0;
    #pragma unroll
    for (int k = 0; k < 10; ++k) {
        int grow = row0 - 1 + k;
        if (grow >= 0 && grow < 56) vmask |= 1u << k;
    }

    // w staging: thread -> (oc = tid>>2 in 0..127, s = tid&3); coalesced global
    const ush* wgl = wagg + (size_t)b * 9 * 65536 + (size_t)(oc0 + (tid >> 2)) * 256 + (tid & 3) * 8;
    ush* wdst = wsh + (tid & 3) * 1024 + (((tid >> 2) ^ ((tid & 3) << 2)) << 3);
    // w frag read: lane (l15,s4), frag mi -> oc = ocH*64 + mi*16 + l15
    const ush* wrd = wsh + s4 * 1024 + (((ocH << 6) + (l15 ^ (s4 << 2))) << 3);
    // x DMA: 512 threads cover 10 rows x 4KB; thread -> (rowpar = tid>>8, col = tid&255)
    int xl = tid & 255, xh = tid >> 8;
    const ush* xb = xT + (size_t)b * 8 * 56 * 2048 + (size_t)xl * 8;

    f32x4 acc[4][7];
    #pragma unroll
    for (int mi = 0; mi < 4; ++mi)
        #pragma unroll
        for (int j = 0; j < 7; ++j) acc[mi][j] = (f32x4)(0.f);

    __syncthreads();                      // x-zero visible

    // ---- prologue: stage chunk 0 ----
    U16B wpre[9];
    #pragma unroll
    for (int k = 0; k < 9; ++k) wpre[k].u = *(const u32x4*)(wgl + (size_t)k * 65536);
    #pragma unroll
    for (int r = 0; r < 5; ++r) {
        int row = r * 2 + xh;
        if ((vmask >> row) & 1)
            gl_lds16(xb + (size_t)(row0 - 1 + row) * 2048, &xs[0][0] + row * 2048 + xl * 8);
    }
    #pragma unroll
    for (int k = 0; k < 9; ++k) *(u32x4*)(wdst + k * 4096) = wpre[k].u;
    __syncthreads();                      // full drain once (prologue only)

    for (int cc = 0; cc < 8; ++cc) {
        // ---- issue next chunk's stage FIRST (hidden under compute) ----
        if (cc < 7) {
            const ush* wgc = wgl + (size_t)(cc + 1) * 32;
            #pragma unroll
            for (int k = 0; k < 9; ++k) wpre[k].u = *(const u32x4*)(wgc + (size_t)k * 65536);
            ush* xdst = &xs[0][0] + ((cc & 1) ^ 1) * 20480;
            #pragma unroll
            for (int r = 0; r < 5; ++r) {
                int row = r * 2 + xh;
                if ((vmask >> row) & 1)
                    gl_lds16(xb + (size_t)((cc + 1) * 56 + row0 - 1 + row) * 2048,
                             xdst + row * 2048 + xl * 8);
            }
        }
        // ---- compute: 9 taps x 28 MFMA from buf[cc&1] + w LDS ----
        const ush* xsb = &xs[0][0] + (cc & 1) * 20480;
        #pragma unroll
        for (int tap = 0; tap < 9; ++tap) {
            const int dy = tap / 3, dx = tap % 3;
            U16B wf[4];
            #pragma unroll
            for (int mi = 0; mi < 4; ++mi)
                wf[mi].u = *(const u32x4*)(wrd + tap * 4096 + mi * 128);
            U16B bx[7];
            #pragma unroll
            for (int j = 0; j < 7; ++j) {
                int q    = pq[j] + dx;
                int slot = s4 ^ ((q >> 1) & 3);
                bx[j].u = *(const u32x4*)(xsb + ((prow[j] + dy) * 64 + q) * 32 + slot * 8);
            }
            __builtin_amdgcn_s_setprio(1);
            #pragma unroll
            for (int j = 0; j < 7; ++j) {
                acc[0][j] = __builtin_amdgcn_mfma_f32_16x16x32_bf16(bx[j].b, wf[0].b, acc[0][j], 0, 0, 0);
                acc[1][j] = __builtin_amdgcn_mfma_f32_16x16x32_bf16(bx[j].b, wf[1].b, acc[1][j], 0, 0, 0);
                acc[2][j] = __builtin_amdgcn_mfma_f32_16x16x32_bf16(bx[j].b, wf[2].b, acc[2][j], 0, 0, 0);
                acc[3][j] = __builtin_amdgcn_mfma_f32_16x16x32_bf16(bx[j].b, wf[3].b, acc[3][j], 0, 0, 0);
            }
            __builtin_amdgcn_s_setprio(0);
        }
        // ---- boundary: own LDS reads done -> barrier (NO vmcnt drain here) --
        asm volatile("s_waitcnt lgkmcnt(0)" ::: "memory");
        __builtin_amdgcn_s_barrier();
        if (cc < 7) {
            // ds_write next w (compiler waits vmcnt for wpre only; DMAs younger)
            #pragma unroll
            for (int k = 0; k < 9; ++k) *(u32x4*)(wdst + k * 4096) = wpre[k].u;
            // x DMAs for cc+1 had a full compute phase of cover -> ~free wait
            asm volatile("s_waitcnt vmcnt(0)" ::: "memory");
            asm volatile("s_waitcnt lgkmcnt(0)" ::: "memory");
            __builtin_amdgcn_s_barrier();
        }
    }

    // epilogue: D row = px (4 consecutive per lane via s4), col = oc (l15)
    int pxbase = row0 * 56 + pxq * 112 + s4 * 4;
    #pragma unroll
    for (int mi = 0; mi < 4; ++mi) {
        int oc = oc0 + ocH * 64 + mi * 16 + l15;
        float* o = out + (size_t)(b * 256 + oc) * HWPX + pxbase;
        #pragma unroll
        for (int j = 0; j < 7; ++j)
            *(f32x4*)(o + j * 16) = acc[mi][j];
    }
}

// ---------------- launcher ----------------
extern "C" void kernel_launch(void* const* d_in, const int* in_sizes, int n_in,
                              void* d_out, int out_size, void* d_ws, size_t ws_size,
                              hipStream_t stream) {
    const float* x     = (const float*)d_in[0];
    const float* cells = (const float*)d_in[1];
    const float* fc1_w = (const float*)d_in[2];
    const float* fc1_b = (const float*)d_in[3];
    const float* ln_g  = (const float*)d_in[4];
    const float* ln_b  = (const float*)d_in[5];
    const float* sp_w  = (const float*)d_in[6];
    const float* sp_b  = (const float*)d_in[7];
    float* out = (float*)d_out;

    char* ws = (char*)d_ws;
    ush*   xT     = (ush*)ws;
    float* pooled = (float*)(ws + POOL_OFF);
    float* att    = (float*)(ws + ATT_OFF);
    ush*   wagg   = (ush*)(ws + WAGG_OFF);

    k_halo<<<448, 256, 0, stream>>>((u32x4*)ws, (u32x4*)pooled);
    k_transpose<<<6272, 256, 0, stream>>>(x, xT, pooled);
    k_attn<<<1, 512, 0, stream>>>(pooled, fc1_w, fc1_b, ln_g, ln_b, sp_w, sp_b, att);
    k_agg<<<2048, 256, 0, stream>>>(cells, att, wagg);
    k_conv<<<448, 512, 0, stream>>>(xT, wagg, out);
}

// Round 12
// 240.609 us; speedup vs baseline: 1.3664x; 1.3664x over previous
//
#include <hip/hip_runtime.h>
#include <stdint.h>

// ---------------- types ----------------
typedef unsigned short ush;
typedef __bf16   bf16x8 __attribute__((ext_vector_type(8)));
typedef float    f32x4  __attribute__((ext_vector_type(4)));
typedef uint32_t u32x4  __attribute__((ext_vector_type(4)));

union U16B { u32x4 u; bf16x8 b; };
union P8   { ush us[8]; u32x4 v; };

template<int V> struct ICx { static constexpr int value = V; };

__device__ __forceinline__ ush f2bf(float f) {
    union { float f; uint32_t u; } v; v.f = f;
    uint32_t r = v.u + 0x7FFFu + ((v.u >> 16) & 1u);   // RNE
    return (ush)(r >> 16);
}

__device__ __forceinline__ void gl_lds16(const ush* g, ush* l) {
    __builtin_amdgcn_global_load_lds(
        (const __attribute__((address_space(1))) uint32_t*)g,
        (__attribute__((address_space(3))) uint32_t*)l, 16, 0, 0);
}

// problem constants
#define HWPX  3136
// ws layout (bytes)
#define POOL_OFF   58720256UL   // 8192 f32
#define ATT_OFF    58753024UL   // 16384 f32
#define WAGG_OFF   58818560UL   // 32*9*256*256 bf16

// ---------------- kernel 1: transpose x -> xT bf16 (swizzled) + pooled sums
//                  + fused halo-zeroing of padcols {0,57} ----------------
// xT layout: [b][icg32 0..7][row 0..55][padcol 0..63][ic 0..31]
//   padcol p: p=0 and p=57 are zero halo; p=1..56 <-> image col p-1; 58..63 dead
//   sub 's' stored at slot s ^ ((p>>1)&3): injective on every 8-col window
__global__ void k_transpose(const float* __restrict__ x, ush* __restrict__ xT,
                            float* __restrict__ pooled) {
    __shared__ float tile[64][65];
    int blk = blockIdx.x;                 // 32 * 4 * 49
    int b   = blk / 196;
    int rem = blk % 196;
    int icg = rem / 49;                   // 64-ic group
    int pxg = rem % 49;                   // 64-px group
    int t = threadIdx.x;

    {
        int icl  = t >> 2, part = t & 3;
        const float* src = x + (size_t)(b * 256 + icg * 64 + icl) * HWPX + pxg * 64 + part * 16;
        #pragma unroll
        for (int k = 0; k < 4; ++k) {
            f32x4 v = *(const f32x4*)(src + k * 4);
            tile[icl][part * 16 + k * 4 + 0] = v[0];
            tile[icl][part * 16 + k * 4 + 1] = v[1];
            tile[icl][part * 16 + k * 4 + 2] = v[2];
            tile[icl][part * 16 + k * 4 + 3] = v[3];
        }
    }

    // fused halo zeroing: rows r whose start px (r*56) falls in this block's
    // 64-px window (each row belongs to exactly one pxg); zero p=0 and p=57
    // for both icg32 lines of this icg.  32 threads: 2 rows x 2 icg32 x 2 cols
    // x 4 16B-chunks.
    if (t < 32) {
        int r = (pxg * 64 + 55) / 56 + (t >> 4);
        if (r < 56 && r * 56 <= pxg * 64 + 63) {
            int icg32 = icg * 2 + ((t >> 3) & 1);
            int colp  = ((t >> 2) & 1) ? 57 : 0;
            int chunk = t & 3;
            u32x4 z = (u32x4)(0u);
            *(u32x4*)(xT + (((size_t)(b * 8 + icg32) * 56 + r) * 64 + colp) * 32 + chunk * 8) = z;
        }
    }
    __syncthreads();

    if (t < 64) {
        float s = 0.f;
        #pragma unroll 8
        for (int p = 0; p < 64; ++p) s += tile[t][p];
        atomicAdd(pooled + b * 256 + icg * 64 + t, s);
    }

    {
        int pxl = t >> 2, icq = t & 3;
        int px  = pxg * 64 + pxl;
        int row = px / 56;
        int col = px - row * 56;
        int p   = col + 1;
        int xorp = (p >> 1) & 3;
        int icg32   = icg * 2 + (icq >> 1);
        int subbase = (icq & 1) * 2;
        P8 lo, hi;
        #pragma unroll
        for (int m = 0; m < 8; ++m) {
            lo.us[m] = f2bf(tile[icq * 16 + m][pxl]);
            hi.us[m] = f2bf(tile[icq * 16 + 8 + m][pxl]);
        }
        size_t base = (((size_t)(b * 8 + icg32) * 56 + row) * 64 + p) * 32;
        *(u32x4*)(xT + base + (size_t)((subbase ^ xorp) * 8))       = lo.v;
        *(u32x4*)(xT + base + (size_t)(((subbase + 1) ^ xorp) * 8)) = hi.v;
    }
}

// ---------------- kernel 2: attention (1 block, 512 threads) ----------------
__global__ void k_attn(const float* __restrict__ pooled,
                       const float* __restrict__ fc1_w, const float* __restrict__ fc1_b,
                       const float* __restrict__ ln_g,  const float* __restrict__ ln_b,
                       const float* __restrict__ sp_w,  const float* __restrict__ sp_b,
                       float* __restrict__ att) {
    __shared__ float hs[32][16];
    int t = threadIdx.x;
    {
        int b = t >> 4, j = t & 15;
        float acc = 0.f;
        for (int c = 0; c < 256; ++c) acc += pooled[b * 256 + c] * fc1_w[j * 256 + c];
        hs[b][j] = fc1_b[j] + acc * (1.0f / 3136.0f);
    }
    __syncthreads();
    if (t < 32) {
        float mu = 0.f;
        #pragma unroll
        for (int j = 0; j < 16; ++j) mu += hs[t][j];
        mu *= (1.0f / 16.0f);
        float var = 0.f;
        #pragma unroll
        for (int j = 0; j < 16; ++j) { float d = hs[t][j] - mu; var += d * d; }
        var *= (1.0f / 16.0f);
        float inv = rsqrtf(var + 1e-5f);
        #pragma unroll
        for (int j = 0; j < 16; ++j) {
            float v = (hs[t][j] - mu) * inv * ln_g[j] + ln_b[j];
            hs[t][j] = fmaxf(v, 0.f);
        }
    }
    __syncthreads();
    {
        int b = t >> 4, m = t & 15;
        float a[33];
        #pragma unroll 1
        for (int i = 0; i < 33; ++i) {
            int p = m * 33 + i;
            float acc = sp_b[p];
            #pragma unroll
            for (int j = 0; j < 16; ++j) acc += hs[b][j] * sp_w[p * 16 + j];
            a[i] = acc;
        }
        float s = 0.f;
        #pragma unroll
        for (int i = 0; i < 33; ++i) s += fabsf(a[i]);
        float inv = 1.0f / (s + 0.001f);
        #pragma unroll
        for (int c = 0; c < 32; ++c) att[(b * 16 + m) * 32 + c] = a[c] * inv;
    }
}

// ---------------- kernel 3: aggregate weights -> Wagg bf16 [b][tap][oc][ic] --
__global__ void k_agg(const float* __restrict__ cells, const float* __restrict__ att,
                      ush* __restrict__ wagg) {
    __shared__ float at[512];
    int blk = blockIdx.x;                 // 32*64
    int b = blk >> 6, co = blk & 63;
    int t = threadIdx.x;
    for (int i = t; i < 512; i += 256) at[i] = att[b * 512 + i];
    __syncthreads();
    int ci = t & 63, gi = t >> 6;
    float acc[4][9];
    #pragma unroll
    for (int g = 0; g < 4; ++g)
        #pragma unroll
        for (int k = 0; k < 9; ++k) acc[g][k] = 0.f;
    for (int c = 0; c < 32; ++c) {
        float a0 = at[(0 + gi) * 32 + c];
        float a1 = at[(4 + gi) * 32 + c];
        float a2 = at[(8 + gi) * 32 + c];
        float a3 = at[(12 + gi) * 32 + c];
        const float* cp = cells + (size_t)c * 36864 + co * 576 + ci * 9;
        #pragma unroll
        for (int k = 0; k < 9; ++k) {
            float cv = cp[k];
            acc[0][k] += a0 * cv; acc[1][k] += a1 * cv;
            acc[2][k] += a2 * cv; acc[3][k] += a3 * cv;
        }
    }
    #pragma unroll
    for (int g = 0; g < 4; ++g)
        #pragma unroll
        for (int k = 0; k < 9; ++k)
            wagg[((size_t)(b * 9 + k) * 256 + g * 64 + co) * 256 + gi * 64 + ci] = f2bf(acc[g][k]);
}

// ---------------- kernel 4: conv, covered-drain double-buffered pipeline ----
// block = 224 px (4 rows) x 64 oc; 4 waves = 2 px-halves x 2 oc-halves
//   (wave = 112 px x 32 oc -> acc[2][7] = 56 AGPR, big VGPR headroom)
// LDS: x DOUBLE buffer [2][6 rows][64 col][32 ic]  = 49,152 B
//      w taps 0..7    [8][4 slots][64 oc] 16B      = 32,768 B  -> 81,920 total
//      (tap 8 weights streamed per-wave from global, issued 8 taps early)
// T3 structure: ALL loads for chunk cc+1 (w->reg, x->DMA into buf^1) are
// issued BEFORE chunk cc's compute, so the vmcnt(0) inside __syncthreads()
// lands after a full compute phase of cover.  Two barriers per chunk, both
// with trivial waits; only serial region is 8 ds_writes.
__global__ __launch_bounds__(256, 2) void k_conv(const ush* __restrict__ xT,
                                                 const ush* __restrict__ wagg,
                                                 float* __restrict__ out) {
    __shared__ __align__(16) ush xs[2][12288];   // 49,152 B
    __shared__ __align__(16) ush wsh[16384];     // 32,768 B

    int tid = threadIdx.x;
    int wg  = blockIdx.x;                // 1792
    int xcd = wg & 7;
    int kk  = wg >> 3;                   // 0..223
    int gq  = kk / 14;                   // 0..15
    int sp  = kk - gq * 14;              // spatial tile 0..13 (4 rows)
    int g   = gq * 8 + xcd;              // 0..127
    int b   = g >> 2, octile = g & 3;
    int row0 = sp * 4, oc0 = octile * 64;

    int lane = tid & 63, w = tid >> 6;
    int wn = w & 1, ocH = w >> 1;        // px half (112), oc half (32)
    int l15 = lane & 15, s4 = lane >> 4;

    {   // zero both x buffers once (invalid halo rows stay zero forever)
        u32x4 z = (u32x4)(0u);
        #pragma unroll
        for (int i = 0; i < 12; ++i) ((u32x4*)xs)[tid + i * 256] = z;
    }

    int prow[7], pq[7];
    #pragma unroll
    for (int j = 0; j < 7; ++j) {
        int px = wn * 112 + j * 16 + l15;
        prow[j] = px / 56;                           // 0..3 local out row
        pq[j]   = px - prow[j] * 56;
    }

    unsigned vmask = 0;
    #pragma unroll
    for (int k = 0; k < 6; ++k) {
        int grow = row0 - 1 + k;
        if (grow >= 0 && grow < 56) vmask |= 1u << k;
    }

    // w staging (taps 0..7): thread -> (oc' = tid>>2, s = tid&3)
    const ush* wgl  = wagg + (size_t)b * 9 * 65536 + (size_t)(oc0 + (tid >> 2)) * 256 + (tid & 3) * 8;
    ush*       wdst = wsh + ((size_t)(tid & 3) * 64 + (tid >> 2)) * 8;  // + tap*2048
    // w frag read: lane (l15,s4), frag mi -> oc' = ocH*32 + mi*16 + l15
    const ush* wrd  = wsh + ((size_t)s4 * 64 + ocH * 32 + l15) * 8;     // + tap*2048 + mi*128
    // tap-8 per-wave global frag base (+ cc*32, + mi*4096)
    const ush* w8gl = wagg + (size_t)(b * 9 + 8) * 65536 + (size_t)(oc0 + ocH * 32 + l15) * 256 + s4 * 8;
    // x DMA source (per-lane 16B within a 4KB row line)
    const ush* xb = xT + (size_t)b * 8 * 56 * 2048 + (size_t)tid * 8;

    f32x4 acc[2][7];
    #pragma unroll
    for (int mi = 0; mi < 2; ++mi)
        #pragma unroll
        for (int j = 0; j < 7; ++j) acc[mi][j] = (f32x4)(0.f);

    __syncthreads();                      // x-zero visible before DMA

    // ---- prologue: stage chunk 0 (uncovered drain, once per block) ----
    {
        U16B wpre[8];
        #pragma unroll
        for (int k = 0; k < 8; ++k) wpre[k].u = *(const u32x4*)(wgl + (size_t)k * 65536);
        #pragma unroll
        for (int k = 0; k < 6; ++k)
            if (vmask & (1u << k))
                gl_lds16(xb + (size_t)(row0 - 1 + k) * 2048, &xs[0][0] + k * 2048 + w * 512);
        __syncthreads();
        #pragma unroll
        for (int k = 0; k < 8; ++k) *(u32x4*)(wdst + k * 2048) = wpre[k].u;
        __syncthreads();
    }

    auto chunk_body = [&](auto parc, int cc) {
        constexpr int PAR = decltype(parc)::value;    // == cc & 1
        // tap-8 wf for THIS chunk: issued first (oldest) -> its wait at tap 8
        // retires nothing else; 8 taps (~2K cyc) of cover.
        U16B wf8[2];
        wf8[0].u = *(const u32x4*)(w8gl + (size_t)cc * 32);
        wf8[1].u = *(const u32x4*)(w8gl + (size_t)cc * 32 + 4096);
        // next chunk's w -> reg and x -> DMA(buf^1): drained at barrier-1,
        // which sits after the full 9-tap compute (covered).
        U16B wpre[8];
        bool pre = cc < 7;
        if (pre) {
            const ush* wgc = wgl + (size_t)(cc + 1) * 32;
            #pragma unroll
            for (int k = 0; k < 8; ++k) wpre[k].u = *(const u32x4*)(wgc + (size_t)k * 65536);
            ush* xo = &xs[0][0] + (PAR ^ 1) * 12288;
            #pragma unroll
            for (int k = 0; k < 6; ++k)
                if (vmask & (1u << k))
                    gl_lds16(xb + (size_t)((cc + 1) * 56 + row0 - 1 + k) * 2048,
                             xo + k * 2048 + w * 512);
        }
        const ush* xsb = &xs[0][0] + PAR * 12288;
        // taps 0..7 from LDS
        #pragma unroll
        for (int tap = 0; tap < 8; ++tap) {
            const int dy = tap / 3, dx = tap % 3;
            U16B wf[2];
            wf[0].u = *(const u32x4*)(wrd + tap * 2048);
            wf[1].u = *(const u32x4*)(wrd + tap * 2048 + 128);
            U16B bx[7];
            #pragma unroll
            for (int j = 0; j < 7; ++j) {
                int q    = pq[j] + dx;
                int slot = s4 ^ ((q >> 1) & 3);
                bx[j].u = *(const u32x4*)(xsb + ((prow[j] + dy) * 64 + q) * 32 + slot * 8);
            }
            __builtin_amdgcn_s_setprio(1);
            #pragma unroll
            for (int j = 0; j < 7; ++j) {
                acc[0][j] = __builtin_amdgcn_mfma_f32_16x16x32_bf16(bx[j].b, wf[0].b, acc[0][j], 0, 0, 0);
                acc[1][j] = __builtin_amdgcn_mfma_f32_16x16x32_bf16(bx[j].b, wf[1].b, acc[1][j], 0, 0, 0);
            }
            __builtin_amdgcn_s_setprio(0);
        }
        {   // tap 8 (dy=2, dx=2) from global-loaded wf8
            U16B bx[7];
            #pragma unroll
            for (int j = 0; j < 7; ++j) {
                int q    = pq[j] + 2;
                int slot = s4 ^ ((q >> 1) & 3);
                bx[j].u = *(const u32x4*)(xsb + ((prow[j] + 2) * 64 + q) * 32 + slot * 8);
            }
            __builtin_amdgcn_s_setprio(1);
            #pragma unroll
            for (int j = 0; j < 7; ++j) {
                acc[0][j] = __builtin_amdgcn_mfma_f32_16x16x32_bf16(bx[j].b, wf8[0].b, acc[0][j], 0, 0, 0);
                acc[1][j] = __builtin_amdgcn_mfma_f32_16x16x32_bf16(bx[j].b, wf8[1].b, acc[1][j], 0, 0, 0);
            }
            __builtin_amdgcn_s_setprio(0);
        }
        __syncthreads();                  // drains (covered) + ends reads of wsh
        if (pre) {
            #pragma unroll
            for (int k = 0; k < 8; ++k) *(u32x4*)(wdst + k * 2048) = wpre[k].u;
            __syncthreads();              // w writes visible; nothing outstanding
        }
    };

    for (int c2 = 0; c2 < 8; c2 += 2) {
        chunk_body(ICx<0>{}, c2);
        chunk_body(ICx<1>{}, c2 + 1);
    }

    // epilogue: D row = px (4 consecutive per lane via s4), col = oc (l15)
    int pxbase = row0 * 56 + wn * 112 + s4 * 4;
    #pragma unroll
    for (int mi = 0; mi < 2; ++mi) {
        int oc = oc0 + ocH * 32 + mi * 16 + l15;
        float* o = out + (size_t)(b * 256 + oc) * HWPX + pxbase;
        #pragma unroll
        for (int j = 0; j < 7; ++j)
            *(f32x4*)(o + j * 16) = acc[mi][j];
    }
}

// ---------------- launcher ----------------
extern "C" void kernel_launch(void* const* d_in, const int* in_sizes, int n_in,
                              void* d_out, int out_size, void* d_ws, size_t ws_size,
                              hipStream_t stream) {
    const float* x     = (const float*)d_in[0];
    const float* cells = (const float*)d_in[1];
    const float* fc1_w = (const float*)d_in[2];
    const float* fc1_b = (const float*)d_in[3];
    const float* ln_g  = (const float*)d_in[4];
    const float* ln_b  = (const float*)d_in[5];
    const float* sp_w  = (const float*)d_in[6];
    const float* sp_b  = (const float*)d_in[7];
    float* out = (float*)d_out;

    char* ws = (char*)d_ws;
    ush*   xT     = (ush*)ws;
    float* pooled = (float*)(ws + POOL_OFF);
    float* att    = (float*)(ws + ATT_OFF);
    ush*   wagg   = (ush*)(ws + WAGG_OFF);

    hipMemsetAsync(pooled, 0, 32768, stream);   // pooled accumulators to zero
    k_transpose<<<6272, 256, 0, stream>>>(x, xT, pooled);
    k_attn<<<1, 512, 0, stream>>>(pooled, fc1_w, fc1_b, ln_g, ln_b, sp_w, sp_b, att);
    k_agg<<<2048, 256, 0, stream>>>(cells, att, wagg);
    k_conv<<<1792, 256, 0, stream>>>(xT, wagg, out);
}

// Round 13
// 237.361 us; speedup vs baseline: 1.3851x; 1.0137x over previous
//
#include <hip/hip_runtime.h>
#include <stdint.h>

// ---------------- types ----------------
typedef unsigned short ush;
typedef __bf16   bf16x8 __attribute__((ext_vector_type(8)));
typedef float    f32x4  __attribute__((ext_vector_type(4)));
typedef uint32_t u32x4  __attribute__((ext_vector_type(4)));

union U16B { u32x4 u; bf16x8 b; };
union P8   { ush us[8]; u32x4 v; };

template<int V> struct ICx { static constexpr int value = V; };

__device__ __forceinline__ ush f2bf(float f) {
    union { float f; uint32_t u; } v; v.f = f;
    uint32_t r = v.u + 0x7FFFu + ((v.u >> 16) & 1u);   // RNE
    return (ush)(r >> 16);
}

__device__ __forceinline__ void gl_lds16(const ush* g, ush* l) {
    __builtin_amdgcn_global_load_lds(
        (const __attribute__((address_space(1))) uint32_t*)g,
        (__attribute__((address_space(3))) uint32_t*)l, 16, 0, 0);
}

// problem constants
#define HWPX  3136
// ws layout (bytes)
#define POOL_OFF   58720256UL   // 8192 f32
#define ATT_OFF    58753024UL   // 16384 f32
#define WAGG_OFF   58818560UL   // 32*9*256*256 bf16

// ---------------- kernel 1: transpose x -> xT bf16 (swizzled) + pooled sums
//                  + fused halo-zeroing of padcols {0,57} ----------------
// xT layout: [b][icg32 0..7][row 0..55][padcol 0..63][ic 0..31]
//   padcol p: p=0 and p=57 are zero halo; p=1..56 <-> image col p-1; 58..63 dead
//   sub 's' stored at slot s ^ ((p>>1)&3): injective on every 8-col window
__global__ void k_transpose(const float* __restrict__ x, ush* __restrict__ xT,
                            float* __restrict__ pooled) {
    __shared__ float tile[64][65];
    int blk = blockIdx.x;                 // 32 * 4 * 49
    int b   = blk / 196;
    int rem = blk % 196;
    int icg = rem / 49;                   // 64-ic group
    int pxg = rem % 49;                   // 64-px group
    int t = threadIdx.x;

    {
        int icl  = t >> 2, part = t & 3;
        const float* src = x + (size_t)(b * 256 + icg * 64 + icl) * HWPX + pxg * 64 + part * 16;
        #pragma unroll
        for (int k = 0; k < 4; ++k) {
            f32x4 v = *(const f32x4*)(src + k * 4);
            tile[icl][part * 16 + k * 4 + 0] = v[0];
            tile[icl][part * 16 + k * 4 + 1] = v[1];
            tile[icl][part * 16 + k * 4 + 2] = v[2];
            tile[icl][part * 16 + k * 4 + 3] = v[3];
        }
    }

    // fused halo zeroing (rows whose start-px lies in this 64-px window)
    if (t < 32) {
        int r = (pxg * 64 + 55) / 56 + (t >> 4);
        if (r < 56 && r * 56 <= pxg * 64 + 63) {
            int icg32 = icg * 2 + ((t >> 3) & 1);
            int colp  = ((t >> 2) & 1) ? 57 : 0;
            int chunk = t & 3;
            u32x4 z = (u32x4)(0u);
            *(u32x4*)(xT + (((size_t)(b * 8 + icg32) * 56 + r) * 64 + colp) * 32 + chunk * 8) = z;
        }
    }
    __syncthreads();

    if (t < 64) {
        float s = 0.f;
        #pragma unroll 8
        for (int p = 0; p < 64; ++p) s += tile[t][p];
        atomicAdd(pooled + b * 256 + icg * 64 + t, s);
    }

    {
        int pxl = t >> 2, icq = t & 3;
        int px  = pxg * 64 + pxl;
        int row = px / 56;
        int col = px - row * 56;
        int p   = col + 1;
        int xorp = (p >> 1) & 3;
        int icg32   = icg * 2 + (icq >> 1);
        int subbase = (icq & 1) * 2;
        P8 lo, hi;
        #pragma unroll
        for (int m = 0; m < 8; ++m) {
            lo.us[m] = f2bf(tile[icq * 16 + m][pxl]);
            hi.us[m] = f2bf(tile[icq * 16 + 8 + m][pxl]);
        }
        size_t base = (((size_t)(b * 8 + icg32) * 56 + row) * 64 + p) * 32;
        *(u32x4*)(xT + base + (size_t)((subbase ^ xorp) * 8))       = lo.v;
        *(u32x4*)(xT + base + (size_t)(((subbase + 1) ^ xorp) * 8)) = hi.v;
    }
}

// ---------------- kernel 2: attention (1 block, 512 threads) ----------------
__global__ void k_attn(const float* __restrict__ pooled,
                       const float* __restrict__ fc1_w, const float* __restrict__ fc1_b,
                       const float* __restrict__ ln_g,  const float* __restrict__ ln_b,
                       const float* __restrict__ sp_w,  const float* __restrict__ sp_b,
                       float* __restrict__ att) {
    __shared__ float hs[32][16];
    int t = threadIdx.x;
    {
        int b = t >> 4, j = t & 15;
        float acc = 0.f;
        for (int c = 0; c < 256; ++c) acc += pooled[b * 256 + c] * fc1_w[j * 256 + c];
        hs[b][j] = fc1_b[j] + acc * (1.0f / 3136.0f);
    }
    __syncthreads();
    if (t < 32) {
        float mu = 0.f;
        #pragma unroll
        for (int j = 0; j < 16; ++j) mu += hs[t][j];
        mu *= (1.0f / 16.0f);
        float var = 0.f;
        #pragma unroll
        for (int j = 0; j < 16; ++j) { float d = hs[t][j] - mu; var += d * d; }
        var *= (1.0f / 16.0f);
        float inv = rsqrtf(var + 1e-5f);
        #pragma unroll
        for (int j = 0; j < 16; ++j) {
            float v = (hs[t][j] - mu) * inv * ln_g[j] + ln_b[j];
            hs[t][j] = fmaxf(v, 0.f);
        }
    }
    __syncthreads();
    {
        int b = t >> 4, m = t & 15;
        float a[33];
        #pragma unroll 1
        for (int i = 0; i < 33; ++i) {
            int p = m * 33 + i;
            float acc = sp_b[p];
            #pragma unroll
            for (int j = 0; j < 16; ++j) acc += hs[b][j] * sp_w[p * 16 + j];
            a[i] = acc;
        }
        float s = 0.f;
        #pragma unroll
        for (int i = 0; i < 33; ++i) s += fabsf(a[i]);
        float inv = 1.0f / (s + 0.001f);
        #pragma unroll
        for (int c = 0; c < 32; ++c) att[(b * 16 + m) * 32 + c] = a[c] * inv;
    }
}

// ---------------- kernel 3: aggregate weights ----------------
// NEW wagg layout: [b][cc(8)][ocg(4)][tap(9)][slot(4)][oc64][ic8]
//   -> per (b,cc,ocg): 9 taps x 2048 ush CONTIGUOUS (DMA-stageable panels)
__global__ void k_agg(const float* __restrict__ cells, const float* __restrict__ att,
                      ush* __restrict__ wagg) {
    __shared__ float at[512];
    int blk = blockIdx.x;                 // 32*64
    int b = blk >> 6, co = blk & 63;
    int t = threadIdx.x;
    for (int i = t; i < 512; i += 256) at[i] = att[b * 512 + i];
    __syncthreads();
    int ci = t & 63, gi = t >> 6;
    float acc[4][9];
    #pragma unroll
    for (int g = 0; g < 4; ++g)
        #pragma unroll
        for (int k = 0; k < 9; ++k) acc[g][k] = 0.f;
    for (int c = 0; c < 32; ++c) {
        float a0 = at[(0 + gi) * 32 + c];
        float a1 = at[(4 + gi) * 32 + c];
        float a2 = at[(8 + gi) * 32 + c];
        float a3 = at[(12 + gi) * 32 + c];
        const float* cp = cells + (size_t)c * 36864 + co * 576 + ci * 9;
        #pragma unroll
        for (int k = 0; k < 9; ++k) {
            float cv = cp[k];
            acc[0][k] += a0 * cv; acc[1][k] += a1 * cv;
            acc[2][k] += a2 * cv; acc[3][k] += a3 * cv;
        }
    }
    int ic  = gi * 64 + ci;
    int cc  = ic >> 5;
    int s   = (ic >> 3) & 3;
    int icw = ic & 7;
    #pragma unroll
    for (int g = 0; g < 4; ++g)
        #pragma unroll
        for (int k = 0; k < 9; ++k)
            wagg[((size_t)(b * 32 + cc * 4 + g) * 9 + k) * 2048 + s * 512 + co * 8 + icw]
                = f2bf(acc[g][k]);
}

// ---------------- kernel 4: conv, all-DMA staged, counted-vmcnt pipeline ----
// block = 224 px (4 rows) x 64 oc; 4 waves = 2 px-halves x 2 oc-halves
// LDS: x dbuf [2][6][64][32] = 49,152 B; w ping-pong [2][4 taps][s][64oc][8ic]
//      = 32,768 B  -> 81,920 total = exactly 2 blocks/CU.
// Per chunk, two groups of 4 taps (tap 8 reg-streamed):
//   EVEN: wf8 loads + w-DMA(taps4-7 -> H1) | [sched_barrier] x-DMA(cc+1) |
//         taps0-3 from H0 | lgkm0 | vmcnt(6) keeps x in flight | barrier
//   ODD : w-DMA(next cc taps0-3 -> H0) | taps4-7 from H1 + tap8 | lgkm0 |
//         vmcnt(0) (x had 8 taps cover) | barrier
// NO ds_writes anywhere; every LDS pattern is the measured-0-conflict family.
__global__ __launch_bounds__(256, 2) void k_conv(const ush* __restrict__ xT,
                                                 const ush* __restrict__ wagg,
                                                 float* __restrict__ out) {
    __shared__ __align__(16) ush xs[2][12288];   // 49,152 B
    __shared__ __align__(16) ush wsh[2][8192];   // 32,768 B

    int tid = threadIdx.x;
    int wg  = blockIdx.x;                // 1792
    int xcd = wg & 7;
    int kk  = wg >> 3;                   // 0..223
    int gq  = kk / 14;                   // 0..15
    int sp  = kk - gq * 14;              // spatial tile 0..13 (4 rows)
    int g   = gq * 8 + xcd;              // 0..127
    int b   = g >> 2, octile = g & 3;
    int row0 = sp * 4, oc0 = octile * 64;

    int lane = tid & 63, w = tid >> 6;
    int wn = w & 1, ocH = w >> 1;        // px half (112), oc half (32)
    int l15 = lane & 15, s4 = lane >> 4;

    {   // zero both x buffers once (invalid halo rows stay zero forever)
        u32x4 z = (u32x4)(0u);
        #pragma unroll
        for (int i = 0; i < 12; ++i) ((u32x4*)xs)[tid + i * 256] = z;
    }

    int prow[7], pq[7];
    #pragma unroll
    for (int j = 0; j < 7; ++j) {
        int px = wn * 112 + j * 16 + l15;
        prow[j] = px / 56;
        pq[j]   = px - prow[j] * 56;
    }

    unsigned vmask = 0;
    #pragma unroll
    for (int k = 0; k < 6; ++k) {
        int grow = row0 - 1 + k;
        if (grow >= 0 && grow < 56) vmask |= 1u << k;
    }
    const bool full6 = (vmask == 0x3Fu);

    // w panel base for this (b, octile); chunk stride 4*9*2048 = 73728 ush
    const ush* wc0 = wagg + ((size_t)b * 32 + octile) * 9 * 2048;
    // w frag read offset within a half: (tapLocal)*2048 + s4*512 + ocl*8 (+mi*128)
    const int  woff = s4 * 512 + (ocH * 32 + l15) * 8;
    // tap-8 per-wave global frag base (+ cc*73728, + mi*128)
    const ush* w8gl = wc0 + 8 * 2048 + woff;
    // x DMA source (per-lane 16B within a 4KB row line)
    const ush* xb = xT + (size_t)b * 8 * 56 * 2048 + (size_t)tid * 8;

    f32x4 acc[2][7];
    #pragma unroll
    for (int mi = 0; mi < 2; ++mi)
        #pragma unroll
        for (int j = 0; j < 7; ++j) acc[mi][j] = (f32x4)(0.f);

    __syncthreads();                      // x-zero visible before DMA

    // ---- prologue: DMA (cc=0, taps0-3) -> H0 and x chunk0 -> xs[0] ----
    #pragma unroll
    for (int k = 0; k < 4; ++k)
        gl_lds16(wc0 + (w * 4 + k) * 512 + lane * 8, &wsh[0][(w * 4 + k) * 512]);
    #pragma unroll
    for (int k = 0; k < 6; ++k)
        if (vmask & (1u << k))
            gl_lds16(xb + (size_t)(row0 - 1 + k) * 2048, &xs[0][k * 2048 + w * 512]);
    __syncthreads();                      // full drain once (prologue only)

    auto do_tap = [&](const ush* xsb, const ush* wfp, int dy, int dx) {
        U16B wf[2];
        wf[0].u = *(const u32x4*)(wfp);
        wf[1].u = *(const u32x4*)(wfp + 128);
        U16B bx[7];
        #pragma unroll
        for (int j = 0; j < 7; ++j) {
            int q    = pq[j] + dx;
            int slot = s4 ^ ((q >> 1) & 3);
            bx[j].u = *(const u32x4*)(xsb + ((prow[j] + dy) * 64 + q) * 32 + slot * 8);
        }
        __builtin_amdgcn_s_setprio(1);
        #pragma unroll
        for (int j = 0; j < 7; ++j) {
            acc[0][j] = __builtin_amdgcn_mfma_f32_16x16x32_bf16(bx[j].b, wf[0].b, acc[0][j], 0, 0, 0);
            acc[1][j] = __builtin_amdgcn_mfma_f32_16x16x32_bf16(bx[j].b, wf[1].b, acc[1][j], 0, 0, 0);
        }
        __builtin_amdgcn_s_setprio(0);
    };

    auto chunk_body = [&](auto parc, int cc) {
        constexpr int PAR = decltype(parc)::value;    // == cc & 1 (x buffer)
        const ush* xsb = &xs[PAR][0];
        const ush* wck = wc0 + (size_t)cc * 73728;

        // ================== group EVEN: taps 0-3 from H0 ==================
        U16B wf8[2];
        wf8[0].u = *(const u32x4*)(w8gl + (size_t)cc * 73728);
        wf8[1].u = *(const u32x4*)(w8gl + (size_t)cc * 73728 + 128);
        #pragma unroll
        for (int k = 0; k < 4; ++k)       // w-DMA: this chunk's taps 4-7 -> H1
            gl_lds16(wck + 8192 + (w * 4 + k) * 512 + lane * 8,
                     &wsh[1][(w * 4 + k) * 512]);
        __builtin_amdgcn_sched_barrier(0); // pin: {wf8, w-DMA} before x-DMA
        if (cc < 7) {                     // x-DMA: next chunk -> other buffer
            #pragma unroll
            for (int k = 0; k < 6; ++k)
                if (vmask & (1u << k))
                    gl_lds16(xb + (size_t)((cc + 1) * 56 + row0 - 1 + k) * 2048,
                             &xs[PAR ^ 1][k * 2048 + w * 512]);
        }
        do_tap(xsb, &wsh[0][0 * 2048 + woff], 0, 0);
        do_tap(xsb, &wsh[0][1 * 2048 + woff], 0, 1);
        do_tap(xsb, &wsh[0][2 * 2048 + woff], 0, 2);
        do_tap(xsb, &wsh[0][3 * 2048 + woff], 1, 0);
        asm volatile("s_waitcnt lgkmcnt(0)" ::: "memory");
        if (cc < 7) {                     // keep x-DMAs in flight (T4)
            if (full6) asm volatile("s_waitcnt vmcnt(6)" ::: "memory");
            else       asm volatile("s_waitcnt vmcnt(5)" ::: "memory");
        } else {
            asm volatile("s_waitcnt vmcnt(0)" ::: "memory");
        }
        __builtin_amdgcn_s_barrier();

        // ================== group ODD: taps 4-7 from H1 + tap 8 ==========
        if (cc < 7) {                     // w-DMA: next chunk's taps 0-3 -> H0
            #pragma unroll
            for (int k = 0; k < 4; ++k)
                gl_lds16(wck + 73728 + (w * 4 + k) * 512 + lane * 8,
                         &wsh[0][(w * 4 + k) * 512]);
        }
        do_tap(xsb, &wsh[1][0 * 2048 + woff], 1, 1);
        do_tap(xsb, &wsh[1][1 * 2048 + woff], 1, 2);
        do_tap(xsb, &wsh[1][2 * 2048 + woff], 2, 0);
        do_tap(xsb, &wsh[1][3 * 2048 + woff], 2, 1);
        {   // tap 8 (dy=2, dx=2) from reg-streamed wf8
            U16B bx[7];
            #pragma unroll
            for (int j = 0; j < 7; ++j) {
                int q    = pq[j] + 2;
                int slot = s4 ^ ((q >> 1) & 3);
                bx[j].u = *(const u32x4*)(xsb + ((prow[j] + 2) * 64 + q) * 32 + slot * 8);
            }
            __builtin_amdgcn_s_setprio(1);
            #pragma unroll
            for (int j = 0; j < 7; ++j) {
                acc[0][j] = __builtin_amdgcn_mfma_f32_16x16x32_bf16(bx[j].b, wf8[0].b, acc[0][j], 0, 0, 0);
                acc[1][j] = __builtin_amdgcn_mfma_f32_16x16x32_bf16(bx[j].b, wf8[1].b, acc[1][j], 0, 0, 0);
            }
            __builtin_amdgcn_s_setprio(0);
        }
        asm volatile("s_waitcnt lgkmcnt(0)" ::: "memory");
        asm volatile("s_waitcnt vmcnt(0)" ::: "memory");
        __builtin_amdgcn_s_barrier();
    };

    for (int c2 = 0; c2 < 8; c2 += 2) {
        chunk_body(ICx<0>{}, c2);
        chunk_body(ICx<1>{}, c2 + 1);
    }

    // epilogue: D row = px (4 consecutive per lane via s4), col = oc (l15)
    int pxbase = row0 * 56 + wn * 112 + s4 * 4;
    #pragma unroll
    for (int mi = 0; mi < 2; ++mi) {
        int oc = oc0 + ocH * 32 + mi * 16 + l15;
        float* o = out + (size_t)(b * 256 + oc) * HWPX + pxbase;
        #pragma unroll
        for (int j = 0; j < 7; ++j)
            *(f32x4*)(o + j * 16) = acc[mi][j];
    }
}

// ---------------- launcher ----------------
extern "C" void kernel_launch(void* const* d_in, const int* in_sizes, int n_in,
                              void* d_out, int out_size, void* d_ws, size_t ws_size,
                              hipStream_t stream) {
    const float* x     = (const float*)d_in[0];
    const float* cells = (const float*)d_in[1];
    const float* fc1_w = (const float*)d_in[2];
    const float* fc1_b = (const float*)d_in[3];
    const float* ln_g  = (const float*)d_in[4];
    const float* ln_b  = (const float*)d_in[5];
    const float* sp_w  = (const float*)d_in[6];
    const float* sp_b  = (const float*)d_in[7];
    float* out = (float*)d_out;

    char* ws = (char*)d_ws;
    ush*   xT     = (ush*)ws;
    float* pooled = (float*)(ws + POOL_OFF);
    float* att    = (float*)(ws + ATT_OFF);
    ush*   wagg   = (ush*)(ws + WAGG_OFF);

    hipMemsetAsync(pooled, 0, 32768, stream);   // pooled accumulators to zero
    k_transpose<<<6272, 256, 0, stream>>>(x, xT, pooled);
    k_attn<<<1, 512, 0, stream>>>(pooled, fc1_w, fc1_b, ln_g, ln_b, sp_w, sp_b, att);
    k_agg<<<2048, 256, 0, stream>>>(cells, att, wagg);
    k_conv<<<1792, 256, 0, stream>>>(xT, wagg, out);
}